// Round 2
// baseline (419.005 us; speedup 1.0000x reference)
//
#include <hip/hip_runtime.h>
#include <stdint.h>

typedef float f4 __attribute__((ext_vector_type(4)));

// fp32 -> bf16(e8m7) round-to-nearest-even with saturation to bf16-max.
// Bit-exact vs reference float_quantize(x, 8, 7) (see round-0 derivation).
__device__ __forceinline__ float bf16_rne(float x) {
    uint32_t u = __float_as_uint(x);
    uint32_t r = (u + 0x7FFFu + ((u >> 16) & 1u)) & 0xFFFF0000u;
    if ((r & 0x7F800000u) == 0x7F800000u)            // overflow -> saturate (inputs finite)
        r = (r & 0x80000000u) | 0x7F7F0000u;         // +/- bf16 max
    return __uint_as_float(r);
}

// Quantize 4 consecutive elements; the 8-element BFP block is this thread's 4
// plus its lane^1 partner's 4 (block max shared via one shfl_xor).
// No m>0 branch needed: a zero block gives E=-127 and rint(ldexp(0,.))==0,
// so zeros fall out naturally; subnormal block-maxes reproduce exactly too
// (values sit on the 2^(E-6) grid for any E >= true floor(log2(m))).
__device__ __forceinline__ f4 quant4(f4 a) {
    float v0 = bf16_rne(a.x), v1 = bf16_rne(a.y);
    float v2 = bf16_rne(a.z), v3 = bf16_rne(a.w);
    float m = fmaxf(fmaxf(fabsf(v0), fabsf(v1)), fmaxf(fabsf(v2), fabsf(v3)));
    m = fmaxf(m, __shfl_xor(m, 1));                  // 8-elem block max (lane pair)
    int E = (int)((__float_as_uint(m) >> 23) & 0xFFu) - 127;  // floor(log2(m)) for bf16 m
    int s_up = 6 - E, s_dn = E - 6;                  // scale = 2^(E-6), exact via v_ldexp_f32
    f4 o;
    o.x = ldexpf(fminf(fmaxf(rintf(ldexpf(v0, s_up)), -127.0f), 127.0f), s_dn);
    o.y = ldexpf(fminf(fmaxf(rintf(ldexpf(v1, s_up)), -127.0f), 127.0f), s_dn);
    o.z = ldexpf(fminf(fmaxf(rintf(ldexpf(v2, s_up)), -127.0f), 127.0f), s_dn);
    o.w = ldexpf(fminf(fmaxf(rintf(ldexpf(v3, s_up)), -127.0f), 127.0f), s_dn);
    return o;
}

// 4 float4s per thread, all loads issued before any use -> 4 outstanding
// global_load_dwordx4 per lane (MLP to cover ~900cyc HBM latency).
// Stride keeps each load/store instruction fully coalesced (16 B/lane).
constexpr int UNROLL = 4;

__global__ __launch_bounds__(256) void bfp_quant_kernel(const f4* __restrict__ in,
                                                        f4* __restrict__ out,
                                                        int n4) {
    int stride = gridDim.x * blockDim.x;
    int base = blockIdx.x * blockDim.x + threadIdx.x;
    f4 a[UNROLL];
#pragma unroll
    for (int u = 0; u < UNROLL; ++u) {
        int idx = base + u * stride;
        if (idx < n4) a[u] = __builtin_nontemporal_load(&in[idx]);
    }
#pragma unroll
    for (int u = 0; u < UNROLL; ++u) {
        int idx = base + u * stride;
        // stride is even and n4 is even, so lane pairs (lane, lane^1) are
        // always both-active or both-inactive -> shfl inside is safe.
        if (idx < n4) {
            f4 o = quant4(a[u]);
            __builtin_nontemporal_store(o, &out[idx]);
        }
    }
}

extern "C" void kernel_launch(void* const* d_in, const int* in_sizes, int n_in,
                              void* d_out, int out_size, void* d_ws, size_t ws_size,
                              hipStream_t stream) {
    const float* x = (const float*)d_in[0];
    float* out = (float*)d_out;
    int n = in_sizes[0];                 // 8*2048*4096 = 2^26 (divisible by 8)
    int n4 = n >> 2;                     // float4 groups, 2^24
    int block = 256;
    int per_block = block * UNROLL;      // 1024 float4s per workgroup
    int grid = (n4 + per_block - 1) / per_block;   // 16384
    bfp_quant_kernel<<<grid, block, 0, stream>>>((const f4*)x, (f4*)out, n4);
}